// Round 3
// baseline (14351.567 us; speedup 1.0000x reference)
//
#include <hip/hip_runtime.h>
#include <hip/hip_bf16.h>

// NSSNN forward on MI355X. x (1,1,31,96,96) fp32. S = 31*96*96 = 285696.
// Chunked conv->scan pipeline: per chunk of 8 scan-channels, conv computes the
// matching gate channels (6 or 4 groups x 8) into a compact g buffer, then the
// fused activation+SRU-scan kernel consumes it. Workspace:
//   g(48*S) | h(16*S) | e0(32*S) | e1(64*S)   (d0 aliases e0 in-place; d1 aliases e1)
//   fp32: 183 MB; if ws_size is smaller, fall back to bf16 storage (91 MB).

#define D_DIM 31
#define H_DIM 96
#define W_DIM 96
#define HW (H_DIM * W_DIM)
#define SVOX (D_DIM * HW)

__device__ __forceinline__ float sigm(float v) { return 1.0f / (1.0f + __expf(-v)); }

template <typename T> __device__ __forceinline__ float ldf(const T* p);
template <> __device__ __forceinline__ float ldf<float>(const float* p) { return *p; }
template <> __device__ __forceinline__ float ldf<__hip_bfloat16>(const __hip_bfloat16* p) {
    return __bfloat162float(*p);
}
template <typename T> __device__ __forceinline__ void stf(T* p, float v);
template <> __device__ __forceinline__ void stf<float>(float* p, float v) { *p = v; }
template <> __device__ __forceinline__ void stf<__hip_bfloat16>(__hip_bfloat16* p, float v) {
    *p = __float2bfloat16(v);
}

// ---------------------------------------------------------------------------
// Direct 3x3x3 conv, pad 1. Block: 256 thr = 16x16 (h,w) tile, one depth slice,
// BC output channels of ONE gate group. blockIdx.z = group index.
// Weight out-channel = gidx*Ch + c0 + o ; compact output channel = gidx*BC + o.
// deconv: weight (C_in, C_out_w, 27) flipped -> w[(ci*C_out_w + oc)*27 + 26-k]
// normal: weight (C_out_w, C_in, 27)         -> w[(oc*C_in + ci)*27 + k]
// ---------------------------------------------------------------------------
template <typename Tin, typename Tout, int BC>
__global__ __launch_bounds__(256) void conv3d_k(const Tin* __restrict__ x,
                                                const float* __restrict__ w,
                                                Tout* __restrict__ out,
                                                int C_in, int C_out_w, int Ch, int c0,
                                                int deconv) {
    __shared__ float tile[3 * 18 * 18];
    __shared__ float wsh[BC * 27];

    const int t = threadIdx.x;
    const int lx = t & 15;
    const int ly = t >> 4;
    const int tx0 = (blockIdx.x % 6) * 16;
    const int ty0 = (blockIdx.x / 6) * 16;
    const int d = blockIdx.y;
    const int gidx = blockIdx.z;
    const int ocw0 = gidx * Ch + c0;  // weight-space channel base
    const int oco0 = gidx * BC;       // compact output channel base

    float acc[BC];
#pragma unroll
    for (int i = 0; i < BC; ++i) acc[i] = 0.0f;

    for (int ci = 0; ci < C_in; ++ci) {
        __syncthreads();  // protect LDS from previous iteration's readers
        for (int i = t; i < BC * 27; i += 256) {
            int o = i / 27, k = i % 27;
            int oc = ocw0 + o;
            wsh[i] = deconv ? w[(ci * C_out_w + oc) * 27 + (26 - k)]
                            : w[(oc * C_in + ci) * 27 + k];
        }
        const Tin* xc = x + (size_t)ci * SVOX;
        for (int i = t; i < 3 * 18 * 18; i += 256) {
            int dz = i / 324;
            int rem = i % 324;
            int r = rem / 18;
            int cc = rem % 18;
            int gd = d + dz - 1;
            int gy = ty0 + r - 1;
            int gx = tx0 + cc - 1;
            float v = 0.0f;
            if ((unsigned)gd < D_DIM && (unsigned)gy < H_DIM && (unsigned)gx < W_DIM)
                v = ldf(xc + (gd * H_DIM + gy) * W_DIM + gx);
            tile[i] = v;
        }
        __syncthreads();
#pragma unroll
        for (int kd = 0; kd < 3; ++kd)
#pragma unroll
            for (int kh = 0; kh < 3; ++kh)
#pragma unroll
                for (int kw = 0; kw < 3; ++kw) {
                    float v = tile[kd * 324 + (ly + kh) * 18 + (lx + kw)];
                    const int k = (kd * 3 + kh) * 3 + kw;
#pragma unroll
                    for (int o = 0; o < BC; ++o)
                        acc[o] = fmaf(v, wsh[o * 27 + k], acc[o]);
                }
    }

    const int hy = ty0 + ly, wx = tx0 + lx;
#pragma unroll
    for (int o = 0; o < BC; ++o)
        stf(out + (size_t)(oco0 + o) * SVOX + d * HW + hy * W_DIM + wx, acc[o]);
}

// ---------------------------------------------------------------------------
// do_sru scan on a chunk: g compact (6*chunk, D, H, W), groups [Wx,ft,ft2,rt,rt2,X].
// out[(c0+c)] = fwd + rev (+ resid). One thread per (c,h,w) column.
// ---------------------------------------------------------------------------
template <typename Tg, typename Tio>
__global__ __launch_bounds__(256) void do_sru_scan_k(const Tg* __restrict__ g,
                                                     const Tio* __restrict__ resid,
                                                     Tio* __restrict__ out,
                                                     int chunk, int c0) {
    int idx = blockIdx.x * blockDim.x + threadIdx.x;
    if (idx >= chunk * HW) return;
    int c = idx / HW, hw = idx % HW;
    const size_t gbase = (size_t)c * SVOX + hw;
    const size_t gs = (size_t)chunk * SVOX;
    const size_t obase = (size_t)(c0 + c) * SVOX + hw;
    const Tg* gW = g + gbase;
    const Tg* gF = g + gs + gbase;
    const Tg* gF2 = g + 2 * gs + gbase;
    const Tg* gR = g + 3 * gs + gbase;
    const Tg* gR2 = g + 4 * gs + gbase;
    const Tg* gX = g + 5 * gs + gbase;

    float hbuf[D_DIM];
    float C = 0.0f;
#pragma unroll
    for (int d = 0; d < D_DIM; ++d) {
        float f = sigm(ldf(gF + d * HW));
        float r = sigm(ldf(gR + d * HW));
        float xv = tanhf(ldf(gX + d * HW));
        float wv = tanhf(ldf(gW + d * HW));
        C = (d == 0) ? (1.0f - f) : (f * C + (1.0f - f) * wv);
        hbuf[d] = r * C + (1.0f - r) * xv;
    }
#pragma unroll
    for (int i = 0; i < D_DIM; ++i) {
        int d = D_DIM - 1 - i;
        float f = sigm(ldf(gF2 + d * HW));
        float r = sigm(ldf(gR2 + d * HW));
        float xv = tanhf(ldf(gX + d * HW));
        float wv = tanhf(ldf(gW + d * HW));
        C = (i == 0) ? (1.0f - f) : (f * C + (1.0f - f) * wv);
        float hv = r * C + (1.0f - r) * xv;
        float res = resid ? ldf(resid + obase + d * HW) : 0.0f;
        hbuf[d] += hv + res;
    }
#pragma unroll
    for (int d = 0; d < D_DIM; ++d) stf(out + obase + d * HW, hbuf[d]);
}

// ---------------------------------------------------------------------------
// si_sru scan on a chunk: g compact (4*chunk, D, H, W), groups [Wx,ft,rt,X].
// Reads resid then writes out at the same element -> safe when out==resid.
// ---------------------------------------------------------------------------
template <typename T, int REV>
__global__ __launch_bounds__(256) void si_sru_scan_k(const T* __restrict__ g,
                                                     const T* __restrict__ resid,
                                                     T* __restrict__ out,
                                                     int chunk, int c0) {
    int idx = blockIdx.x * blockDim.x + threadIdx.x;
    if (idx >= chunk * HW) return;
    int c = idx / HW, hw = idx % HW;
    const size_t gbase = (size_t)c * SVOX + hw;
    const size_t gs = (size_t)chunk * SVOX;
    const size_t obase = (size_t)(c0 + c) * SVOX + hw;
    const T* gW = g + gbase;
    const T* gF = g + gs + gbase;
    const T* gR = g + 2 * gs + gbase;
    const T* gX = g + 3 * gs + gbase;

    float C = 0.0f;
#pragma unroll
    for (int i = 0; i < D_DIM; ++i) {
        int d = REV ? (D_DIM - 1 - i) : i;
        float f = sigm(ldf(gF + d * HW));
        float r = sigm(ldf(gR + d * HW));
        float xv = tanhf(ldf(gX + d * HW));
        float wv = tanhf(ldf(gW + d * HW));
        C = (i == 0) ? (1.0f - f) : (f * C + (1.0f - f) * wv);
        float hv = r * C + (1.0f - r) * xv;
        float o = hv + (resid ? ldf(resid + obase + d * HW) : 0.0f);
        stf(out + obase + d * HW, o);
    }
}

// ---------------------------------------------------------------------------
template <typename T>
static void run_net(const float* x, const float* w_head, const float* w_e0,
                    const float* w_e1, const float* w_d0, const float* w_d1,
                    const float* w_tail, float* out, void* d_ws, hipStream_t stream) {
    T* g  = (T*)d_ws;                 // 48*S
    T* H  = g + (size_t)48 * SVOX;    // 16*S
    T* E0 = H + (size_t)16 * SVOX;    // 32*S (d0 written in-place here)
    T* E1 = E0 + (size_t)32 * SVOX;   // 64*S (d1 aliases first 16*S)
    T* D0 = E0;
    T* D1 = E1;

    dim3 blk(256);
    const dim3 sg8(8 * 36);  // 8*HW/256 blocks

    // 1. head: conv 1->96 (Ch=16, 6 groups), do_sru -> H
    for (int c0 = 0; c0 < 16; c0 += 8) {
        conv3d_k<float, T, 8><<<dim3(36, 31, 6), blk, 0, stream>>>(x, w_head, g, 1, 96, 16, c0, 0);
        do_sru_scan_k<T, T><<<sg8, blk, 0, stream>>>(g, (const T*)nullptr, H, 8, c0);
    }
    // 2. e0: conv 16->128 (Ch=32, 4 groups), si_sru fwd -> E0
    for (int c0 = 0; c0 < 32; c0 += 8) {
        conv3d_k<T, T, 8><<<dim3(36, 31, 4), blk, 0, stream>>>(H, w_e0, g, 16, 128, 32, c0, 0);
        si_sru_scan_k<T, 0><<<sg8, blk, 0, stream>>>(g, (const T*)nullptr, E0, 8, c0);
    }
    // 3. e1: conv 32->256 (Ch=64, 4 groups), si_sru rev -> E1
    for (int c0 = 0; c0 < 64; c0 += 8) {
        conv3d_k<T, T, 8><<<dim3(36, 31, 4), blk, 0, stream>>>(E0, w_e1, g, 32, 256, 64, c0, 0);
        si_sru_scan_k<T, 1><<<sg8, blk, 0, stream>>>(g, (const T*)nullptr, E1, 8, c0);
    }
    // 4. d0: deconv 64->128 (Ch=32), si_sru fwd + e0 -> D0 (in-place over E0)
    for (int c0 = 0; c0 < 32; c0 += 8) {
        conv3d_k<T, T, 8><<<dim3(36, 31, 4), blk, 0, stream>>>(E1, w_d0, g, 64, 128, 32, c0, 1);
        si_sru_scan_k<T, 0><<<sg8, blk, 0, stream>>>(g, E0, D0, 8, c0);
    }
    // 5. d1: deconv 32->64 (Ch=16), si_sru rev + h -> D1 (over dead E1)
    for (int c0 = 0; c0 < 16; c0 += 8) {
        conv3d_k<T, T, 8><<<dim3(36, 31, 4), blk, 0, stream>>>(D0, w_d1, g, 32, 64, 16, c0, 1);
        si_sru_scan_k<T, 1><<<sg8, blk, 0, stream>>>(g, H, D1, 8, c0);
    }
    // 6. tail: deconv 16->6 (Ch=1, 6 groups of 1), do_sru + x -> out (fp32)
    conv3d_k<T, T, 1><<<dim3(36, 31, 6), blk, 0, stream>>>(D1, w_tail, g, 16, 6, 1, 0, 1);
    do_sru_scan_k<T, float><<<dim3(36), blk, 0, stream>>>(g, x, out, 1, 0);
}

extern "C" void kernel_launch(void* const* d_in, const int* in_sizes, int n_in,
                              void* d_out, int out_size, void* d_ws, size_t ws_size,
                              hipStream_t stream) {
    const float* x      = (const float*)d_in[0];
    const float* w_head = (const float*)d_in[1];  // (96, 1, 27)
    const float* w_e0   = (const float*)d_in[2];  // (128, 16, 27)
    const float* w_e1   = (const float*)d_in[3];  // (256, 32, 27)
    const float* w_d0   = (const float*)d_in[4];  // (64, 128, 27)  deconv
    const float* w_d1   = (const float*)d_in[5];  // (32, 64, 27)   deconv
    const float* w_tail = (const float*)d_in[6];  // (16, 6, 27)    deconv
    float* out = (float*)d_out;

    const size_t need_f32 = (size_t)160 * SVOX * sizeof(float);  // ~183 MB
    if (ws_size >= need_f32)
        run_net<float>(x, w_head, w_e0, w_e1, w_d0, w_d1, w_tail, out, d_ws, stream);
    else
        run_net<__hip_bfloat16>(x, w_head, w_e0, w_e1, w_d0, w_d1, w_tail, out, d_ws, stream);
}